// Round 1
// baseline (4157.232 us; speedup 1.0000x reference)
//
#include <hip/hip_runtime.h>
#include <hip/hip_bf16.h>
#include <math.h>

// Problem constants
#define Bd   16
#define NPd  512
#define Nd   1024
#define Cd   1024
#define Hd   16
#define HDd  64
#define HIDd 4096
#define EPSd 1e-5f

// ---------------------------------------------------------------------------
// build_src: per batch row, src[b*N+n] = rank of n among True slots (the token
// index written there), or -1 if slot keeps cache. Detects u8 vs i32 mask
// storage: u8 layout <=> exactly NP nonzero bytes in the row's first N bytes.
// u8 check runs FIRST so we never read past a 16KB u8 buffer as i32.
// ---------------------------------------------------------------------------
__global__ __launch_bounds__(256) void build_src(const void* __restrict__ mask_raw,
                                                 int* __restrict__ src) {
    const int b = blockIdx.x;
    const int t = threadIdx.x;
    const unsigned char* m8 = (const unsigned char*)mask_raw;
    const int* m32 = (const int*)mask_raw;

    // count nonzero bytes assuming u8
    int c = 0;
    #pragma unroll
    for (int i = 0; i < 4; i++) c += (m8[b * Nd + t * 4 + i] != 0) ? 1 : 0;
    #pragma unroll
    for (int off = 1; off < 64; off <<= 1) c += __shfl_xor(c, off);
    __shared__ int warr[4];
    if ((t & 63) == 0) warr[t >> 6] = c;
    __syncthreads();
    const int c8 = warr[0] + warr[1] + warr[2] + warr[3];
    const bool use8 = (c8 == NPd);

    int f[4];
    #pragma unroll
    for (int i = 0; i < 4; i++) {
        const int n = t * 4 + i;
        f[i] = use8 ? (m8[b * Nd + n] != 0) : (m32[b * Nd + n] != 0);
    }
    const int loc = f[0] + f[1] + f[2] + f[3];

    // inclusive wave scan of loc
    int sc_ = loc;
    #pragma unroll
    for (int off = 1; off < 64; off <<= 1) {
        const int u = __shfl_up(sc_, off);
        if ((t & 63) >= off) sc_ += u;
    }
    __shared__ int wtot[4];
    __syncthreads();
    if ((t & 63) == 63) wtot[t >> 6] = sc_;
    __syncthreads();
    int base = 0;
    for (int w = 0; w < (t >> 6); w++) base += wtot[w];

    int run = base + sc_ - loc;   // exclusive prefix for this thread's 4 slots
    #pragma unroll
    for (int i = 0; i < 4; i++) {
        const int n = t * 4 + i;
        src[b * Nd + n] = f[i] ? run : -1;
        run += f[i];
    }
}

// ---------------------------------------------------------------------------
// LayerNorm over C=1024: one block (256 thr) per row, float4 vectorized.
// ---------------------------------------------------------------------------
__global__ __launch_bounds__(256) void ln_kernel(const float* __restrict__ x,
                                                 const float* __restrict__ g,
                                                 const float* __restrict__ bb,
                                                 float* __restrict__ out) {
    const int row = blockIdx.x;
    const int t = threadIdx.x;
    const float* xr = x + (size_t)row * Cd;
    const float4 v = *(const float4*)(xr + t * 4);
    float s = v.x + v.y + v.z + v.w;
    float q = v.x * v.x + v.y * v.y + v.z * v.z + v.w * v.w;
    #pragma unroll
    for (int off = 1; off < 64; off <<= 1) {
        s += __shfl_xor(s, off);
        q += __shfl_xor(q, off);
    }
    __shared__ float ss[4], qq[4];
    if ((t & 63) == 0) { ss[t >> 6] = s; qq[t >> 6] = q; }
    __syncthreads();
    s = ss[0] + ss[1] + ss[2] + ss[3];
    q = qq[0] + qq[1] + qq[2] + qq[3];
    const float mu = s * (1.0f / Cd);
    const float var = q * (1.0f / Cd) - mu * mu;
    const float rs = rsqrtf(var + EPSd);
    const float4 gv = *(const float4*)(g + t * 4);
    const float4 bv = *(const float4*)(bb + t * 4);
    float4 r;
    r.x = (v.x - mu) * rs * gv.x + bv.x;
    r.y = (v.y - mu) * rs * gv.y + bv.y;
    r.z = (v.z - mu) * rs * gv.z + bv.z;
    r.w = (v.w - mu) * rs * gv.w + bv.w;
    *(float4*)(out + (size_t)row * Cd + t * 4) = r;
}

// ---------------------------------------------------------------------------
// Tiled fp32 GEMM: out[M,Nn] = A[M,K] @ W[K,Nn] + bias (+epilogue)
// 64x64 tile, BK=16, 256 threads, 4x4 microtile. All dims multiples of 64/16.
// EPI: 0 = bias, 1 = bias + residual, 2 = bias + exact GELU
// ---------------------------------------------------------------------------
template <int EPI>
__global__ __launch_bounds__(256) void gemm_tiled(const float* __restrict__ A,
                                                  const float* __restrict__ W,
                                                  const float* __restrict__ bias,
                                                  const float* __restrict__ res,
                                                  float* __restrict__ out,
                                                  int K, int Nn) {
    __shared__ float As[16][68];
    __shared__ float Ws[16][68];
    const int t = threadIdx.x;
    const int tx = t & 15, ty = t >> 4;
    const int m0 = blockIdx.y * 64;
    const int n0 = blockIdx.x * 64;
    float acc[4][4] = {};

    const int arow = t >> 2, ac4 = (t & 3) * 4;
    const int wk = t >> 4, wn4 = (t & 15) * 4;
    const float* Aptr = A + (size_t)(m0 + arow) * K + ac4;
    const float* Wptr = W + (size_t)wk * Nn + n0 + wn4;

    for (int kt = 0; kt < K; kt += 16) {
        const float4 av = *(const float4*)(Aptr + kt);
        const float4 wv = *(const float4*)(Wptr + (size_t)kt * Nn);
        __syncthreads();
        As[ac4 + 0][arow] = av.x;
        As[ac4 + 1][arow] = av.y;
        As[ac4 + 2][arow] = av.z;
        As[ac4 + 3][arow] = av.w;
        *(float4*)&Ws[wk][wn4] = wv;
        __syncthreads();
        #pragma unroll
        for (int k = 0; k < 16; k++) {
            const float4 a = *(const float4*)&As[k][ty * 4];
            const float4 b = *(const float4*)&Ws[k][tx * 4];
            acc[0][0] += a.x * b.x; acc[0][1] += a.x * b.y; acc[0][2] += a.x * b.z; acc[0][3] += a.x * b.w;
            acc[1][0] += a.y * b.x; acc[1][1] += a.y * b.y; acc[1][2] += a.y * b.z; acc[1][3] += a.y * b.w;
            acc[2][0] += a.z * b.x; acc[2][1] += a.z * b.y; acc[2][2] += a.z * b.z; acc[2][3] += a.z * b.w;
            acc[3][0] += a.w * b.x; acc[3][1] += a.w * b.y; acc[3][2] += a.w * b.z; acc[3][3] += a.w * b.w;
        }
    }

    const float4 bv = *(const float4*)(bias + n0 + tx * 4);
    #pragma unroll
    for (int i = 0; i < 4; i++) {
        const size_t row = (size_t)(m0 + ty * 4 + i);
        float v0 = acc[i][0] + bv.x;
        float v1 = acc[i][1] + bv.y;
        float v2 = acc[i][2] + bv.z;
        float v3 = acc[i][3] + bv.w;
        if (EPI == 2) {
            v0 = 0.5f * v0 * (1.0f + erff(v0 * 0.70710678118654752f));
            v1 = 0.5f * v1 * (1.0f + erff(v1 * 0.70710678118654752f));
            v2 = 0.5f * v2 * (1.0f + erff(v2 * 0.70710678118654752f));
            v3 = 0.5f * v3 * (1.0f + erff(v3 * 0.70710678118654752f));
        }
        if (EPI == 1) {
            const float4 rv = *(const float4*)(res + row * Nn + n0 + tx * 4);
            v0 += rv.x; v1 += rv.y; v2 += rv.z; v3 += rv.w;
        }
        float4 r; r.x = v0; r.y = v1; r.z = v2; r.w = v3;
        *(float4*)(out + row * Nn + n0 + tx * 4) = r;
    }
}

// ---------------------------------------------------------------------------
// Flash-style attention. Grid: (qt=16, h=16, b=16). Block 256 threads.
// Q tile = 32 queries x 64 dims. K/V tiles of 64 keys gathered from cache or
// qkv (new tokens) by src[]. Online softmax; thread (r,s) owns query row
// r=t>>3, dims d0=(t&7)*8..+8, and computes scores for keys j = s + 8*j8.
// ---------------------------------------------------------------------------
__global__ __launch_bounds__(256) void attn_kernel(const float* __restrict__ qkv,
                                                   const float* __restrict__ cache_k,
                                                   const float* __restrict__ cache_v,
                                                   const int* __restrict__ srcArr,
                                                   float* __restrict__ attno) {
    const int qt = blockIdx.x;
    const int hh = blockIdx.y;
    const int b = blockIdx.z;
    const int t = threadIdx.x;
    const int lane = t & 63;
    const int r = t >> 3;        // query row in tile [0,32)
    const int s = t & 7;         // sub-lane [0,8)
    const int d0 = s * 8;        // owned dims

    __shared__ float Qs[32][68];
    __shared__ float Ks[64][68];
    __shared__ float Vs[64][68];

    // Load Q tile (scaled by 1/sqrt(HD) = 0.125)
    #pragma unroll
    for (int i = 0; i < 2; i++) {
        const int f = t + i * 256;           // [0,512) float4 ids
        const int qr = f >> 4, c4 = f & 15;
        const float4 qv = *(const float4*)(qkv + ((size_t)(b * NPd + qt * 32 + qr)) * (3 * Cd) + hh * HDd + c4 * 4);
        float4 qs; qs.x = qv.x * 0.125f; qs.y = qv.y * 0.125f; qs.z = qv.z * 0.125f; qs.w = qv.w * 0.125f;
        *(float4*)&Qs[qr][c4 * 4] = qs;
    }

    float o[8] = {};
    float m_run = -INFINITY;
    float l_run = 0.0f;

    for (int kt = 0; kt < 16; kt++) {
        __syncthreads();   // prev tile consumed (and Q visible on first iter)
        // Load K/V tiles (gathered)
        #pragma unroll
        for (int i = 0; i < 4; i++) {
            const int f = t + i * 256;       // [0,1024) float4 ids
            const int krow = f >> 4, c4 = f & 15;
            const int n = kt * 64 + krow;
            const int sidx = srcArr[b * Nd + n];
            const float* kp = (sidx >= 0)
                ? qkv + ((size_t)(b * NPd + sidx)) * (3 * Cd) + Cd + hh * HDd
                : cache_k + ((size_t)((b * Hd + hh) * Nd + n)) * HDd;
            const float* vp = (sidx >= 0)
                ? qkv + ((size_t)(b * NPd + sidx)) * (3 * Cd) + 2 * Cd + hh * HDd
                : cache_v + ((size_t)((b * Hd + hh) * Nd + n)) * HDd;
            *(float4*)&Ks[krow][c4 * 4] = *(const float4*)(kp + c4 * 4);
            *(float4*)&Vs[krow][c4 * 4] = *(const float4*)(vp + c4 * 4);
        }
        __syncthreads();

        // Scores for keys j = s + 8*j8
        float sc[8] = {};
        #pragma unroll
        for (int d4 = 0; d4 < 16; d4++) {
            const float4 q4 = *(const float4*)&Qs[r][d4 * 4];
            #pragma unroll
            for (int j8 = 0; j8 < 8; j8++) {
                const int j = s + 8 * j8;
                const float4 k4 = *(const float4*)&Ks[j][d4 * 4];
                sc[j8] += q4.x * k4.x + q4.y * k4.y + q4.z * k4.z + q4.w * k4.w;
            }
        }

        // Online softmax update (row reduction across the 8 s-lanes)
        float mt = sc[0];
        #pragma unroll
        for (int j8 = 1; j8 < 8; j8++) mt = fmaxf(mt, sc[j8]);
        mt = fmaxf(mt, __shfl_xor(mt, 1));
        mt = fmaxf(mt, __shfl_xor(mt, 2));
        mt = fmaxf(mt, __shfl_xor(mt, 4));
        const float mn = fmaxf(m_run, mt);
        const float alpha = __expf(m_run - mn);
        float p[8];
        float ps = 0.0f;
        #pragma unroll
        for (int j8 = 0; j8 < 8; j8++) { p[j8] = __expf(sc[j8] - mn); ps += p[j8]; }
        ps += __shfl_xor(ps, 1);
        ps += __shfl_xor(ps, 2);
        ps += __shfl_xor(ps, 4);
        l_run = l_run * alpha + ps;
        m_run = mn;
        #pragma unroll
        for (int d = 0; d < 8; d++) o[d] *= alpha;

        // O accumulation: broadcast p across the row's 8 lanes
        #pragma unroll
        for (int j8 = 0; j8 < 8; j8++) {
            #pragma unroll
            for (int sp = 0; sp < 8; sp++) {
                const float pv = __shfl(p[j8], (lane & 56) | sp);
                const int j = sp + 8 * j8;
                const float4 va = *(const float4*)&Vs[j][d0];
                const float4 vb = *(const float4*)&Vs[j][d0 + 4];
                o[0] += pv * va.x; o[1] += pv * va.y; o[2] += pv * va.z; o[3] += pv * va.w;
                o[4] += pv * vb.x; o[5] += pv * vb.y; o[6] += pv * vb.z; o[7] += pv * vb.w;
            }
        }
    }

    const float inv = 1.0f / l_run;
    float4 oa, ob;
    oa.x = o[0] * inv; oa.y = o[1] * inv; oa.z = o[2] * inv; oa.w = o[3] * inv;
    ob.x = o[4] * inv; ob.y = o[5] * inv; ob.z = o[6] * inv; ob.w = o[7] * inv;
    float* op = attno + ((size_t)(b * NPd + qt * 32 + r)) * Cd + hh * HDd + d0;
    *(float4*)op = oa;
    *(float4*)(op + 4) = ob;
}

// ---------------------------------------------------------------------------
extern "C" void kernel_launch(void* const* d_in, const int* in_sizes, int n_in,
                              void* d_out, int out_size, void* d_ws, size_t ws_size,
                              hipStream_t stream) {
    const float* x       = (const float*)d_in[0];
    const float* cache_k = (const float*)d_in[1];
    const float* cache_v = (const float*)d_in[2];
    const void*  mask    = d_in[3];
    const float* qkv_w   = (const float*)d_in[4];
    const float* qkv_b   = (const float*)d_in[5];
    const float* proj_w  = (const float*)d_in[6];
    const float* proj_b  = (const float*)d_in[7];
    const float* n1_g    = (const float*)d_in[8];
    const float* n1_b    = (const float*)d_in[9];
    const float* n2_g    = (const float*)d_in[10];
    const float* n2_b    = (const float*)d_in[11];
    const float* fc1_w   = (const float*)d_in[12];
    const float* fc1_b   = (const float*)d_in[13];
    const float* fc2_w   = (const float*)d_in[14];
    const float* fc2_b   = (const float*)d_in[15];
    float* out = (float*)d_out;

    char* ws = (char*)d_ws;
    int*   srcArr = (int*)ws;                              // 16384 ints (64KB)
    float* x2     = (float*)(ws + 65536);                  // 8.4M floats
    float* h      = x2 + (size_t)Bd * NPd * Cd;            // 8.4M floats (h, then h2)
    float* qkv    = h + (size_t)Bd * NPd * Cd;             // 25.2M floats
    float* attno  = qkv + (size_t)Bd * NPd * 3 * Cd;       // 8.4M floats
    float* m1     = qkv;                                   // 33.6M floats, overlaps dead qkv+attno

    const int Mrows = Bd * NPd;  // 8192

    build_src<<<Bd, 256, 0, stream>>>(mask, srcArr);
    ln_kernel<<<Mrows, 256, 0, stream>>>(x, n1_g, n1_b, h);
    gemm_tiled<0><<<dim3(3 * Cd / 64, Mrows / 64), 256, 0, stream>>>(h, qkv_w, qkv_b, nullptr, qkv, Cd, 3 * Cd);
    attn_kernel<<<dim3(16, Hd, Bd), 256, 0, stream>>>(qkv, cache_k, cache_v, srcArr, attno);
    gemm_tiled<1><<<dim3(Cd / 64, Mrows / 64), 256, 0, stream>>>(attno, proj_w, proj_b, x, x2, Cd, Cd);
    ln_kernel<<<Mrows, 256, 0, stream>>>(x2, n2_g, n2_b, h);
    gemm_tiled<2><<<dim3(HIDd / 64, Mrows / 64), 256, 0, stream>>>(h, fc1_w, fc1_b, nullptr, m1, Cd, HIDd);
    gemm_tiled<1><<<dim3(Cd / 64, Mrows / 64), 256, 0, stream>>>(m1, fc2_w, fc2_b, x2, out, HIDd, Cd);
}

// Round 2
// 1435.635 us; speedup vs baseline: 2.8957x; 2.8957x over previous
//
#include <hip/hip_runtime.h>
#include <hip/hip_bf16.h>
#include <math.h>

// Problem constants
#define Bd   16
#define NPd  512
#define Nd   1024
#define Cd   1024
#define Hd   16
#define HDd  64
#define HIDd 4096
#define EPSd 1e-5f

typedef unsigned short u16;
typedef __bf16 bf16x8 __attribute__((ext_vector_type(8)));
typedef float  f32x4  __attribute__((ext_vector_type(4)));

// round-to-nearest-even f32 -> bf16 bits
__device__ __forceinline__ u16 f2bf(float f) {
    unsigned int u = __builtin_bit_cast(unsigned int, f);
    u = u + 0x7fffu + ((u >> 16) & 1u);
    return (u16)(u >> 16);
}

// async global->LDS, 16B per lane; LDS dest = wave-uniform base + lane*16.
__device__ __forceinline__ void async_load16(const void* g, void* l) {
    __builtin_amdgcn_global_load_lds(
        (const __attribute__((address_space(1))) void*)(uintptr_t)g,
        (__attribute__((address_space(3))) void*)(unsigned int)(uintptr_t)l,
        16, 0, 0);
}

// ---------------------------------------------------------------------------
// build_src: src[b*N+n] = token rank if slot updated else -1 (u8/i32 autodetect)
// ---------------------------------------------------------------------------
__global__ __launch_bounds__(256) void build_src(const void* __restrict__ mask_raw,
                                                 int* __restrict__ src) {
    const int b = blockIdx.x;
    const int t = threadIdx.x;
    const unsigned char* m8 = (const unsigned char*)mask_raw;
    const int* m32 = (const int*)mask_raw;

    int c = 0;
    #pragma unroll
    for (int i = 0; i < 4; i++) c += (m8[b * Nd + t * 4 + i] != 0) ? 1 : 0;
    #pragma unroll
    for (int off = 1; off < 64; off <<= 1) c += __shfl_xor(c, off);
    __shared__ int warr[4];
    if ((t & 63) == 0) warr[t >> 6] = c;
    __syncthreads();
    const int c8 = warr[0] + warr[1] + warr[2] + warr[3];
    const bool use8 = (c8 == NPd);

    int f[4];
    #pragma unroll
    for (int i = 0; i < 4; i++) {
        const int n = t * 4 + i;
        f[i] = use8 ? (m8[b * Nd + n] != 0) : (m32[b * Nd + n] != 0);
    }
    const int loc = f[0] + f[1] + f[2] + f[3];

    int sc_ = loc;
    #pragma unroll
    for (int off = 1; off < 64; off <<= 1) {
        const int u = __shfl_up(sc_, off);
        if ((t & 63) >= off) sc_ += u;
    }
    __shared__ int wtot[4];
    __syncthreads();
    if ((t & 63) == 63) wtot[t >> 6] = sc_;
    __syncthreads();
    int base = 0;
    for (int w = 0; w < (t >> 6); w++) base += wtot[w];

    int run = base + sc_ - loc;
    #pragma unroll
    for (int i = 0; i < 4; i++) {
        const int n = t * 4 + i;
        src[b * Nd + n] = f[i] ? run : -1;
        run += f[i];
    }
}

// ---------------------------------------------------------------------------
// LayerNorm over C=1024 -> bf16 output. One block (256 thr) per row.
// ---------------------------------------------------------------------------
__global__ __launch_bounds__(256) void ln_kernel(const float* __restrict__ x,
                                                 const float* __restrict__ g,
                                                 const float* __restrict__ bb,
                                                 u16* __restrict__ out) {
    const int row = blockIdx.x;
    const int t = threadIdx.x;
    const float* xr = x + (size_t)row * Cd;
    const float4 v = *(const float4*)(xr + t * 4);
    float s = v.x + v.y + v.z + v.w;
    float q = v.x * v.x + v.y * v.y + v.z * v.z + v.w * v.w;
    #pragma unroll
    for (int off = 1; off < 64; off <<= 1) {
        s += __shfl_xor(s, off);
        q += __shfl_xor(q, off);
    }
    __shared__ float ss[4], qq[4];
    if ((t & 63) == 0) { ss[t >> 6] = s; qq[t >> 6] = q; }
    __syncthreads();
    s = ss[0] + ss[1] + ss[2] + ss[3];
    q = qq[0] + qq[1] + qq[2] + qq[3];
    const float mu = s * (1.0f / Cd);
    const float var = q * (1.0f / Cd) - mu * mu;
    const float rs = rsqrtf(var + EPSd);
    const float4 gv = *(const float4*)(g + t * 4);
    const float4 bv = *(const float4*)(bb + t * 4);
    ushort4 r;
    r.x = f2bf((v.x - mu) * rs * gv.x + bv.x);
    r.y = f2bf((v.y - mu) * rs * gv.y + bv.y);
    r.z = f2bf((v.z - mu) * rs * gv.z + bv.z);
    r.w = f2bf((v.w - mu) * rs * gv.w + bv.w);
    *(ushort4*)(out + (size_t)row * Cd + t * 4) = r;
}

// ---------------------------------------------------------------------------
// Weight convert+transpose: W[K,N] f32 -> Wt[N,K] bf16. 32x32 tiles.
// ---------------------------------------------------------------------------
__global__ __launch_bounds__(256) void conv_t(const float* __restrict__ W,
                                              u16* __restrict__ Wt,
                                              int K, int N) {
    __shared__ float tile[32][33];
    const int k0 = blockIdx.y * 32;
    const int n0 = blockIdx.x * 32;
    const int t = threadIdx.x;
    const int row = t >> 3, c4 = (t & 7) * 4;
    const float4 v = *(const float4*)(W + (size_t)(k0 + row) * N + n0 + c4);
    tile[row][c4 + 0] = v.x;
    tile[row][c4 + 1] = v.y;
    tile[row][c4 + 2] = v.z;
    tile[row][c4 + 3] = v.w;
    __syncthreads();
    ushort4 o;
    o.x = f2bf(tile[c4 + 0][row]);
    o.y = f2bf(tile[c4 + 1][row]);
    o.z = f2bf(tile[c4 + 2][row]);
    o.w = f2bf(tile[c4 + 3][row]);
    *(ushort4*)(Wt + (size_t)(n0 + row) * K + k0 + c4) = o;
}

// ---------------------------------------------------------------------------
// bf16 MFMA GEMM (m97 recipe): C[M,Nn] = A[M,K] @ Wt[Nn,K]^T + bias (+epi)
// 128x128 tile, BK=32, 256 thr = 4 waves, each wave 64x64 via 4x4 mfma tiles.
// EPI: 0 = bias, 1 = bias + fp32 residual, 2 = bias + exact GELU
// OUT_T: float or u16 (bf16 bits)
// ---------------------------------------------------------------------------
template <int EPI, typename OUT_T>
__global__ __launch_bounds__(256) void gemm_mfma(const u16* __restrict__ A,
                                                 const u16* __restrict__ Wt,
                                                 const float* __restrict__ bias,
                                                 const float* __restrict__ res,
                                                 OUT_T* __restrict__ out,
                                                 int K, int Nn) {
    __shared__ u16 As[128 * 32];   // [m][k] row-major, 64B rows
    __shared__ u16 Bs[128 * 32];   // [n][k] row-major

    const int t = threadIdx.x;
    const int L = t & 63;
    const int w = t >> 6;
    const int wm = w >> 1, wn = w & 1;
    const int m0 = blockIdx.y * 128;
    const int n0 = blockIdx.x * 128;

    // staging: wave w covers rows [32w, 32w+32), two 16-row issues each
    const int srow = 32 * w + (L >> 2);
    const int scol = (L & 3) * 8;
    const u16* ap0 = A  + (size_t)(m0 + srow) * K + scol;
    const u16* ap1 = ap0 + (size_t)16 * K;
    const u16* bp0 = Wt + (size_t)(n0 + srow) * K + scol;
    const u16* bp1 = bp0 + (size_t)16 * K;
    u16* alds0 = As + w * 1024;           // 2048B per wave
    u16* alds1 = alds0 + 512;
    u16* blds0 = Bs + w * 1024;
    u16* blds1 = blds0 + 512;

    f32x4 acc[4][4];
    const f32x4 zero = {0.f, 0.f, 0.f, 0.f};
    #pragma unroll
    for (int i = 0; i < 4; i++)
        #pragma unroll
        for (int j = 0; j < 4; j++) acc[i][j] = zero;

    const int frag_off = (L & 15) * 32 + (L >> 4) * 8;

    for (int kt = 0; kt < K; kt += 32) {
        __syncthreads();                       // prev tile consumed
        async_load16(ap0 + kt, alds0);
        async_load16(ap1 + kt, alds1);
        async_load16(bp0 + kt, blds0);
        async_load16(bp1 + kt, blds1);
        __syncthreads();                       // compiler drains vmcnt before barrier

        bf16x8 a[4], b[4];
        #pragma unroll
        for (int i = 0; i < 4; i++) {
            a[i] = *(const bf16x8*)&As[(wm * 64 + i * 16) * 32 + frag_off];
            b[i] = *(const bf16x8*)&Bs[(wn * 64 + i * 16) * 32 + frag_off];
        }
        #pragma unroll
        for (int i = 0; i < 4; i++)
            #pragma unroll
            for (int j = 0; j < 4; j++)
                acc[i][j] = __builtin_amdgcn_mfma_f32_16x16x32_bf16(a[i], b[j], acc[i][j], 0, 0, 0);
    }

    // epilogue: lane L, reg r -> C[m0+wm*64+i*16+(L>>4)*4+r][n0+wn*64+j*16+(L&15)]
    const int cn = n0 + wn * 64 + (L & 15);
    const int cm = m0 + wm * 64 + (L >> 4) * 4;
    #pragma unroll
    for (int i = 0; i < 4; i++) {
        #pragma unroll
        for (int j = 0; j < 4; j++) {
            const int nn = cn + j * 16;
            const float bv = bias[nn];
            #pragma unroll
            for (int r = 0; r < 4; r++) {
                const int mm = cm + i * 16 + r;
                float v = acc[i][j][r] + bv;
                if (EPI == 2) v = 0.5f * v * (1.0f + erff(v * 0.70710678118654752f));
                if (EPI == 1) v += res[(size_t)mm * Nn + nn];
                if constexpr (sizeof(OUT_T) == 2) out[(size_t)mm * Nn + nn] = (OUT_T)f2bf(v);
                else out[(size_t)mm * Nn + nn] = v;
            }
        }
    }
}

// ---------------------------------------------------------------------------
// Flash-style attention (fp32), bf16 output. Grid (qt=16, h=16, b=16), 256 thr.
// ---------------------------------------------------------------------------
__global__ __launch_bounds__(256) void attn_kernel(const float* __restrict__ qkv,
                                                   const float* __restrict__ cache_k,
                                                   const float* __restrict__ cache_v,
                                                   const int* __restrict__ srcArr,
                                                   u16* __restrict__ attno) {
    const int qt = blockIdx.x;
    const int hh = blockIdx.y;
    const int b = blockIdx.z;
    const int t = threadIdx.x;
    const int lane = t & 63;
    const int r = t >> 3;
    const int s = t & 7;
    const int d0 = s * 8;

    __shared__ float Qs[32][68];
    __shared__ float Ks[64][68];
    __shared__ float Vs[64][68];

    #pragma unroll
    for (int i = 0; i < 2; i++) {
        const int f = t + i * 256;
        const int qr = f >> 4, c4 = f & 15;
        const float4 qv = *(const float4*)(qkv + ((size_t)(b * NPd + qt * 32 + qr)) * (3 * Cd) + hh * HDd + c4 * 4);
        float4 qs; qs.x = qv.x * 0.125f; qs.y = qv.y * 0.125f; qs.z = qv.z * 0.125f; qs.w = qv.w * 0.125f;
        *(float4*)&Qs[qr][c4 * 4] = qs;
    }

    float o[8] = {};
    float m_run = -INFINITY;
    float l_run = 0.0f;

    for (int kt = 0; kt < 16; kt++) {
        __syncthreads();
        #pragma unroll
        for (int i = 0; i < 4; i++) {
            const int f = t + i * 256;
            const int krow = f >> 4, c4 = f & 15;
            const int n = kt * 64 + krow;
            const int sidx = srcArr[b * Nd + n];
            const float* kp = (sidx >= 0)
                ? qkv + ((size_t)(b * NPd + sidx)) * (3 * Cd) + Cd + hh * HDd
                : cache_k + ((size_t)((b * Hd + hh) * Nd + n)) * HDd;
            const float* vp = (sidx >= 0)
                ? qkv + ((size_t)(b * NPd + sidx)) * (3 * Cd) + 2 * Cd + hh * HDd
                : cache_v + ((size_t)((b * Hd + hh) * Nd + n)) * HDd;
            *(float4*)&Ks[krow][c4 * 4] = *(const float4*)(kp + c4 * 4);
            *(float4*)&Vs[krow][c4 * 4] = *(const float4*)(vp + c4 * 4);
        }
        __syncthreads();

        float sc[8] = {};
        #pragma unroll
        for (int d4 = 0; d4 < 16; d4++) {
            const float4 q4 = *(const float4*)&Qs[r][d4 * 4];
            #pragma unroll
            for (int j8 = 0; j8 < 8; j8++) {
                const int j = s + 8 * j8;
                const float4 k4 = *(const float4*)&Ks[j][d4 * 4];
                sc[j8] += q4.x * k4.x + q4.y * k4.y + q4.z * k4.z + q4.w * k4.w;
            }
        }

        float mt = sc[0];
        #pragma unroll
        for (int j8 = 1; j8 < 8; j8++) mt = fmaxf(mt, sc[j8]);
        mt = fmaxf(mt, __shfl_xor(mt, 1));
        mt = fmaxf(mt, __shfl_xor(mt, 2));
        mt = fmaxf(mt, __shfl_xor(mt, 4));
        const float mn = fmaxf(m_run, mt);
        const float alpha = __expf(m_run - mn);
        float p[8];
        float ps = 0.0f;
        #pragma unroll
        for (int j8 = 0; j8 < 8; j8++) { p[j8] = __expf(sc[j8] - mn); ps += p[j8]; }
        ps += __shfl_xor(ps, 1);
        ps += __shfl_xor(ps, 2);
        ps += __shfl_xor(ps, 4);
        l_run = l_run * alpha + ps;
        m_run = mn;
        #pragma unroll
        for (int d = 0; d < 8; d++) o[d] *= alpha;

        #pragma unroll
        for (int j8 = 0; j8 < 8; j8++) {
            #pragma unroll
            for (int sp = 0; sp < 8; sp++) {
                const float pv = __shfl(p[j8], (lane & 56) | sp);
                const int j = sp + 8 * j8;
                const float4 va = *(const float4*)&Vs[j][d0];
                const float4 vb = *(const float4*)&Vs[j][d0 + 4];
                o[0] += pv * va.x; o[1] += pv * va.y; o[2] += pv * va.z; o[3] += pv * va.w;
                o[4] += pv * vb.x; o[5] += pv * vb.y; o[6] += pv * vb.z; o[7] += pv * vb.w;
            }
        }
    }

    const float inv = 1.0f / l_run;
    ushort4 pa, pb;
    pa.x = f2bf(o[0] * inv); pa.y = f2bf(o[1] * inv); pa.z = f2bf(o[2] * inv); pa.w = f2bf(o[3] * inv);
    pb.x = f2bf(o[4] * inv); pb.y = f2bf(o[5] * inv); pb.z = f2bf(o[6] * inv); pb.w = f2bf(o[7] * inv);
    u16* op = attno + ((size_t)(b * NPd + qt * 32 + r)) * Cd + hh * HDd + d0;
    *(ushort4*)op = pa;
    *(ushort4*)(op + 4) = pb;
}

// ---------------------------------------------------------------------------
extern "C" void kernel_launch(void* const* d_in, const int* in_sizes, int n_in,
                              void* d_out, int out_size, void* d_ws, size_t ws_size,
                              hipStream_t stream) {
    const float* x       = (const float*)d_in[0];
    const float* cache_k = (const float*)d_in[1];
    const float* cache_v = (const float*)d_in[2];
    const void*  mask    = d_in[3];
    const float* qkv_w   = (const float*)d_in[4];
    const float* qkv_b   = (const float*)d_in[5];
    const float* proj_w  = (const float*)d_in[6];
    const float* proj_b  = (const float*)d_in[7];
    const float* n1_g    = (const float*)d_in[8];
    const float* n1_b    = (const float*)d_in[9];
    const float* n2_g    = (const float*)d_in[10];
    const float* n2_b    = (const float*)d_in[11];
    const float* fc1_w   = (const float*)d_in[12];
    const float* fc1_b   = (const float*)d_in[13];
    const float* fc2_w   = (const float*)d_in[14];
    const float* fc2_b   = (const float*)d_in[15];
    float* out = (float*)d_out;

    const size_t MR = (size_t)Bd * NPd;           // 8192 rows
    char* ws = (char*)d_ws;
    int*   srcArr = (int*)ws;                                     // 64 KB
    float* x2     = (float*)(ws + 65536);                         // 33.55 MB fp32
    u16*   h      = (u16*)(x2 + MR * Cd);                         // 16.78 MB bf16 (h, then h2)
    u16*   attno  = h + MR * Cd;                                  // 16.78 MB bf16
    float* qkv    = (float*)(attno + MR * Cd);                    // 100.66 MB fp32
    u16*   m1     = (u16*)qkv;                                    // 67.1 MB bf16, reuses dead qkv
    u16*   qkv_wt = (u16*)(qkv + MR * 3 * Cd);                    // 6.29 MB
    u16*   proj_wt= qkv_wt + (size_t)3 * Cd * Cd;                 // 2.10 MB
    u16*   fc1_wt = proj_wt + (size_t)Cd * Cd;                    // 8.39 MB
    u16*   fc2_wt = fc1_wt + (size_t)Cd * HIDd;                   // 8.39 MB

    build_src<<<Bd, 256, 0, stream>>>(mask, srcArr);
    conv_t<<<dim3(3 * Cd / 32, Cd / 32),  256, 0, stream>>>(qkv_w,  qkv_wt,  Cd,   3 * Cd);
    conv_t<<<dim3(Cd / 32, Cd / 32),      256, 0, stream>>>(proj_w, proj_wt, Cd,   Cd);
    conv_t<<<dim3(HIDd / 32, Cd / 32),    256, 0, stream>>>(fc1_w,  fc1_wt,  Cd,   HIDd);
    conv_t<<<dim3(Cd / 32, HIDd / 32),    256, 0, stream>>>(fc2_w,  fc2_wt,  HIDd, Cd);

    ln_kernel<<<MR, 256, 0, stream>>>(x, n1_g, n1_b, h);
    gemm_mfma<0, float><<<dim3(3 * Cd / 128, MR / 128), 256, 0, stream>>>(h, qkv_wt, qkv_b, nullptr, qkv, Cd, 3 * Cd);
    attn_kernel<<<dim3(16, Hd, Bd), 256, 0, stream>>>(qkv, cache_k, cache_v, srcArr, attno);
    gemm_mfma<1, float><<<dim3(Cd / 128, MR / 128), 256, 0, stream>>>(attno, proj_wt, proj_b, x, x2, Cd, Cd);
    ln_kernel<<<MR, 256, 0, stream>>>(x2, n2_g, n2_b, h);
    gemm_mfma<2, u16><<<dim3(HIDd / 128, MR / 128), 256, 0, stream>>>(h, fc1_wt, fc1_b, nullptr, m1, Cd, HIDd);
    gemm_mfma<1, float><<<dim3(Cd / 128, MR / 128), 256, 0, stream>>>(m1, fc2_wt, fc2_b, x2, out, HIDd, Cd);
}

// Round 3
// 703.277 us; speedup vs baseline: 5.9112x; 2.0414x over previous
//
#include <hip/hip_runtime.h>
#include <hip/hip_bf16.h>
#include <math.h>

// Problem constants
#define Bd   16
#define NPd  512
#define Nd   1024
#define Cd   1024
#define Hd   16
#define HDd  64
#define HIDd 4096
#define EPSd 1e-5f

typedef unsigned short u16;
typedef __bf16 bf16x8 __attribute__((ext_vector_type(8)));
typedef float  f32x4  __attribute__((ext_vector_type(4)));

// round-to-nearest-even f32 -> bf16 bits
__device__ __forceinline__ u16 f2bf(float f) {
    unsigned int u = __builtin_bit_cast(unsigned int, f);
    u = u + 0x7fffu + ((u >> 16) & 1u);
    return (u16)(u >> 16);
}

// async global->LDS, 16B per lane; LDS dest = wave-uniform base + lane*16.
__device__ __forceinline__ void async_load16(const void* g, void* l) {
    __builtin_amdgcn_global_load_lds(
        (const __attribute__((address_space(1))) void*)(uintptr_t)g,
        (__attribute__((address_space(3))) void*)(unsigned int)(uintptr_t)l,
        16, 0, 0);
}

// ---------------------------------------------------------------------------
// build_src: src[b*N+n] = token rank if slot updated else -1 (u8/i32 autodetect)
// ---------------------------------------------------------------------------
__global__ __launch_bounds__(256) void build_src(const void* __restrict__ mask_raw,
                                                 int* __restrict__ src) {
    const int b = blockIdx.x;
    const int t = threadIdx.x;
    const unsigned char* m8 = (const unsigned char*)mask_raw;
    const int* m32 = (const int*)mask_raw;

    int c = 0;
    #pragma unroll
    for (int i = 0; i < 4; i++) c += (m8[b * Nd + t * 4 + i] != 0) ? 1 : 0;
    #pragma unroll
    for (int off = 1; off < 64; off <<= 1) c += __shfl_xor(c, off);
    __shared__ int warr[4];
    if ((t & 63) == 0) warr[t >> 6] = c;
    __syncthreads();
    const int c8 = warr[0] + warr[1] + warr[2] + warr[3];
    const bool use8 = (c8 == NPd);

    int f[4];
    #pragma unroll
    for (int i = 0; i < 4; i++) {
        const int n = t * 4 + i;
        f[i] = use8 ? (m8[b * Nd + n] != 0) : (m32[b * Nd + n] != 0);
    }
    const int loc = f[0] + f[1] + f[2] + f[3];

    int sc_ = loc;
    #pragma unroll
    for (int off = 1; off < 64; off <<= 1) {
        const int u = __shfl_up(sc_, off);
        if ((t & 63) >= off) sc_ += u;
    }
    __shared__ int wtot[4];
    __syncthreads();
    if ((t & 63) == 63) wtot[t >> 6] = sc_;
    __syncthreads();
    int base = 0;
    for (int w = 0; w < (t >> 6); w++) base += wtot[w];

    int run = base + sc_ - loc;
    #pragma unroll
    for (int i = 0; i < 4; i++) {
        const int n = t * 4 + i;
        src[b * Nd + n] = f[i] ? run : -1;
        run += f[i];
    }
}

// ---------------------------------------------------------------------------
// LayerNorm over C=1024 -> bf16 output. One block (256 thr) per row.
// ---------------------------------------------------------------------------
__global__ __launch_bounds__(256) void ln_kernel(const float* __restrict__ x,
                                                 const float* __restrict__ g,
                                                 const float* __restrict__ bb,
                                                 u16* __restrict__ out) {
    const int row = blockIdx.x;
    const int t = threadIdx.x;
    const float* xr = x + (size_t)row * Cd;
    const float4 v = *(const float4*)(xr + t * 4);
    float s = v.x + v.y + v.z + v.w;
    float q = v.x * v.x + v.y * v.y + v.z * v.z + v.w * v.w;
    #pragma unroll
    for (int off = 1; off < 64; off <<= 1) {
        s += __shfl_xor(s, off);
        q += __shfl_xor(q, off);
    }
    __shared__ float ss[4], qq[4];
    if ((t & 63) == 0) { ss[t >> 6] = s; qq[t >> 6] = q; }
    __syncthreads();
    s = ss[0] + ss[1] + ss[2] + ss[3];
    q = qq[0] + qq[1] + qq[2] + qq[3];
    const float mu = s * (1.0f / Cd);
    const float var = q * (1.0f / Cd) - mu * mu;
    const float rs = rsqrtf(var + EPSd);
    const float4 gv = *(const float4*)(g + t * 4);
    const float4 bv = *(const float4*)(bb + t * 4);
    ushort4 r;
    r.x = f2bf((v.x - mu) * rs * gv.x + bv.x);
    r.y = f2bf((v.y - mu) * rs * gv.y + bv.y);
    r.z = f2bf((v.z - mu) * rs * gv.z + bv.z);
    r.w = f2bf((v.w - mu) * rs * gv.w + bv.w);
    *(ushort4*)(out + (size_t)row * Cd + t * 4) = r;
}

// ---------------------------------------------------------------------------
// Weight convert+transpose: W[K,N] f32 -> Wt[N,K] bf16. 32x32 tiles.
// ---------------------------------------------------------------------------
__global__ __launch_bounds__(256) void conv_t(const float* __restrict__ W,
                                              u16* __restrict__ Wt,
                                              int K, int N) {
    __shared__ float tile[32][33];
    const int k0 = blockIdx.y * 32;
    const int n0 = blockIdx.x * 32;
    const int t = threadIdx.x;
    const int row = t >> 3, c4 = (t & 7) * 4;
    const float4 v = *(const float4*)(W + (size_t)(k0 + row) * N + n0 + c4);
    tile[row][c4 + 0] = v.x;
    tile[row][c4 + 1] = v.y;
    tile[row][c4 + 2] = v.z;
    tile[row][c4 + 3] = v.w;
    __syncthreads();
    ushort4 o;
    o.x = f2bf(tile[c4 + 0][row]);
    o.y = f2bf(tile[c4 + 1][row]);
    o.z = f2bf(tile[c4 + 2][row]);
    o.w = f2bf(tile[c4 + 3][row]);
    *(ushort4*)(Wt + (size_t)(n0 + row) * K + k0 + c4) = o;
}

// ---------------------------------------------------------------------------
// bf16 MFMA GEMM (m97 recipe): C[M,Nn] = A[M,K] @ Wt[Nn,K]^T + bias (+epi)
// EPI: 0 = bias, 1 = bias + fp32 residual, 2 = bias + exact GELU
// ---------------------------------------------------------------------------
template <int EPI, typename OUT_T>
__global__ __launch_bounds__(256) void gemm_mfma(const u16* __restrict__ A,
                                                 const u16* __restrict__ Wt,
                                                 const float* __restrict__ bias,
                                                 const float* __restrict__ res,
                                                 OUT_T* __restrict__ out,
                                                 int K, int Nn) {
    __shared__ u16 As[128 * 32];
    __shared__ u16 Bs[128 * 32];

    const int t = threadIdx.x;
    const int L = t & 63;
    const int w = t >> 6;
    const int wm = w >> 1, wn = w & 1;
    const int m0 = blockIdx.y * 128;
    const int n0 = blockIdx.x * 128;

    const int srow = 32 * w + (L >> 2);
    const int scol = (L & 3) * 8;
    const u16* ap0 = A  + (size_t)(m0 + srow) * K + scol;
    const u16* ap1 = ap0 + (size_t)16 * K;
    const u16* bp0 = Wt + (size_t)(n0 + srow) * K + scol;
    const u16* bp1 = bp0 + (size_t)16 * K;
    u16* alds0 = As + w * 1024;
    u16* alds1 = alds0 + 512;
    u16* blds0 = Bs + w * 1024;
    u16* blds1 = blds0 + 512;

    f32x4 acc[4][4];
    const f32x4 zero = {0.f, 0.f, 0.f, 0.f};
    #pragma unroll
    for (int i = 0; i < 4; i++)
        #pragma unroll
        for (int j = 0; j < 4; j++) acc[i][j] = zero;

    const int frag_off = (L & 15) * 32 + (L >> 4) * 8;

    for (int kt = 0; kt < K; kt += 32) {
        __syncthreads();
        async_load16(ap0 + kt, alds0);
        async_load16(ap1 + kt, alds1);
        async_load16(bp0 + kt, blds0);
        async_load16(bp1 + kt, blds1);
        __syncthreads();

        bf16x8 a[4], b[4];
        #pragma unroll
        for (int i = 0; i < 4; i++) {
            a[i] = *(const bf16x8*)&As[(wm * 64 + i * 16) * 32 + frag_off];
            b[i] = *(const bf16x8*)&Bs[(wn * 64 + i * 16) * 32 + frag_off];
        }
        #pragma unroll
        for (int i = 0; i < 4; i++)
            #pragma unroll
            for (int j = 0; j < 4; j++)
                acc[i][j] = __builtin_amdgcn_mfma_f32_16x16x32_bf16(a[i], b[j], acc[i][j], 0, 0, 0);
    }

    const int cn = n0 + wn * 64 + (L & 15);
    const int cm = m0 + wm * 64 + (L >> 4) * 4;
    #pragma unroll
    for (int i = 0; i < 4; i++) {
        #pragma unroll
        for (int j = 0; j < 4; j++) {
            const int nn = cn + j * 16;
            const float bv = bias[nn];
            #pragma unroll
            for (int r = 0; r < 4; r++) {
                const int mm = cm + i * 16 + r;
                float v = acc[i][j][r] + bv;
                if (EPI == 2) v = 0.5f * v * (1.0f + erff(v * 0.70710678118654752f));
                if (EPI == 1) v += res[(size_t)mm * Nn + nn];
                if constexpr (sizeof(OUT_T) == 2) out[(size_t)mm * Nn + nn] = (OUT_T)f2bf(v);
                else out[(size_t)mm * Nn + nn] = v;
            }
        }
    }
}

// ---------------------------------------------------------------------------
// kv_cast: gather full K/V (cache or new tokens via src) into bf16:
//   Kb[B,H,N,HD]  (K rows)    Vtb[B,H,HD,N]  (V transposed)
// Grid: B*H*(N/64) blocks, 256 threads. LDS transpose for V.
// ---------------------------------------------------------------------------
__global__ __launch_bounds__(256) void kv_cast(const u16* __restrict__ qkv,
                                               const float* __restrict__ ck,
                                               const float* __restrict__ cv,
                                               const int* __restrict__ srcArr,
                                               u16* __restrict__ Kb,
                                               u16* __restrict__ Vtb) {
    const int id = blockIdx.x;
    const int nt = id & 15, hh = (id >> 4) & 15, b = id >> 8;
    const int t = threadIdx.x;
    __shared__ u16 Vl[64][72];

    const int row = t >> 2;            // key row 0..63
    const int dd = (t & 3) * 16;       // dim chunk
    const int n = nt * 64 + row;
    const int sidx = srcArr[b * Nd + n];

    u16 kv16[16], vv16[16];
    if (sidx >= 0) {
        const u16* kp = qkv + (size_t)(b * NPd + sidx) * 3072 + Cd + hh * 64 + dd;
        const u16* vp = kp + Cd;
        *(ulonglong2*)&kv16[0] = *(const ulonglong2*)kp;
        *(ulonglong2*)&kv16[8] = *(const ulonglong2*)(kp + 8);
        *(ulonglong2*)&vv16[0] = *(const ulonglong2*)vp;
        *(ulonglong2*)&vv16[8] = *(const ulonglong2*)(vp + 8);
    } else {
        const float* kp = ck + ((size_t)((b * Hd + hh) * Nd + n)) * HDd + dd;
        const float* vp = cv + ((size_t)((b * Hd + hh) * Nd + n)) * HDd + dd;
        #pragma unroll
        for (int c = 0; c < 4; c++) {
            const float4 kc4 = *(const float4*)(kp + c * 4);
            const float4 vc4 = *(const float4*)(vp + c * 4);
            kv16[c * 4 + 0] = f2bf(kc4.x); kv16[c * 4 + 1] = f2bf(kc4.y);
            kv16[c * 4 + 2] = f2bf(kc4.z); kv16[c * 4 + 3] = f2bf(kc4.w);
            vv16[c * 4 + 0] = f2bf(vc4.x); vv16[c * 4 + 1] = f2bf(vc4.y);
            vv16[c * 4 + 2] = f2bf(vc4.z); vv16[c * 4 + 3] = f2bf(vc4.w);
        }
    }

    u16* ko = Kb + ((size_t)((b * Hd + hh) * Nd + n)) * HDd + dd;
    *(ulonglong2*)ko = *(ulonglong2*)&kv16[0];
    *(ulonglong2*)(ko + 8) = *(ulonglong2*)&kv16[8];

    #pragma unroll
    for (int i = 0; i < 16; i++) Vl[row][dd + i] = vv16[i];
    __syncthreads();

    const int d = t >> 2, nc = (t & 3) * 16;
    u16 ov[16];
    #pragma unroll
    for (int i = 0; i < 16; i++) ov[i] = Vl[nc + i][d];
    u16* vo = Vtb + ((size_t)((b * Hd + hh) * HDd + d)) * Nd + nt * 64 + nc;
    *(ulonglong2*)vo = *(ulonglong2*)&ov[0];
    *(ulonglong2*)(vo + 8) = *(ulonglong2*)&ov[8];
}

// ---------------------------------------------------------------------------
// MFMA flash attention. Grid (bh=256, qt=8), 256 thr = 4 waves.
// Each wave owns 16 queries; per 64-key tile: QK^T (8 mfma), online softmax,
// P->LDS->A-frag, PV (8 mfma). LDS tiles XOR-swizzled (chunk ^= row&7) so
// global_load_lds staging and frag reads are both conflict-lite.
// ---------------------------------------------------------------------------
__global__ __launch_bounds__(256) void attn_mfma(const u16* __restrict__ qkv,
                                                 const u16* __restrict__ Kb,
                                                 const u16* __restrict__ Vtb,
                                                 u16* __restrict__ attno) {
    const int bh = blockIdx.x;
    const int qt = blockIdx.y;
    const int b = bh >> 4, hh = bh & 15;
    const int t = threadIdx.x;
    const int L = t & 63;
    const int w = t >> 6;

    __shared__ u16 Qs[4096];          // [64 q][64 k] swizzled
    __shared__ u16 Ks[4096];          // [64 key][64 dim] swizzled
    __shared__ u16 Vs[4096];          // [64 dim][64 key] swizzled
    __shared__ u16 Ps[4][16 * 72];    // per-wave P [16 q][64 key], pad 72

    const size_t kbase = (size_t)((b * Hd + hh) * Nd) * HDd;
    const size_t vbase = (size_t)((b * Hd + hh) * HDd) * Nd;

    // stage Q once (8 issues of 8 rows; wave w does rows 16w..16w+15)
    #pragma unroll
    for (int j = 0; j < 2; j++) {
        const int row = 16 * w + 8 * j + (L >> 3);
        const int ch = (L & 7) ^ (row & 7);
        const u16* g = qkv + (size_t)(b * NPd + qt * 64 + row) * 3072 + hh * 64 + ch * 8;
        async_load16(g, Qs + (16 * w + 8 * j) * 64);
    }

    f32x4 acc[4];
    const f32x4 zero = {0.f, 0.f, 0.f, 0.f};
    #pragma unroll
    for (int nb = 0; nb < 4; nb++) acc[nb] = zero;
    float m_run[4] = {-INFINITY, -INFINITY, -INFINITY, -INFINITY};
    float l_run[4] = {0.f, 0.f, 0.f, 0.f};

    for (int kt = 0; kt < 16; kt++) {
        __syncthreads();    // prev tile consumed
        #pragma unroll
        for (int j = 0; j < 2; j++) {
            const int row = 16 * w + 8 * j + (L >> 3);
            const int ch = (L & 7) ^ (row & 7);
            async_load16(Kb + kbase + (size_t)(kt * 64 + row) * 64 + ch * 8,
                         Ks + (16 * w + 8 * j) * 64);
            async_load16(Vtb + vbase + (size_t)row * Nd + kt * 64 + ch * 8,
                         Vs + (16 * w + 8 * j) * 64);
        }
        __syncthreads();    // staging (and Q on kt=0) complete

        // Q A-frags (rows w*16 + (L&15))
        const int qrow = 16 * w + (L & 15);
        const bf16x8 aq0 = *(const bf16x8*)&Qs[qrow * 64 + (((L >> 4)     ^ (L & 7)) * 8)];
        const bf16x8 aq1 = *(const bf16x8*)&Qs[qrow * 64 + (((4 + (L >> 4)) ^ (L & 7)) * 8)];

        // S = Q K^T  (4 key-blocks of 16)
        f32x4 s[4];
        #pragma unroll
        for (int kb = 0; kb < 4; kb++) {
            const int krow = kb * 16 + (L & 15);
            const bf16x8 bk0 = *(const bf16x8*)&Ks[krow * 64 + (((L >> 4)     ^ (L & 7)) * 8)];
            const bf16x8 bk1 = *(const bf16x8*)&Ks[krow * 64 + (((4 + (L >> 4)) ^ (L & 7)) * 8)];
            s[kb] = __builtin_amdgcn_mfma_f32_16x16x32_bf16(aq0, bk0, zero, 0, 0, 0);
            s[kb] = __builtin_amdgcn_mfma_f32_16x16x32_bf16(aq1, bk1, s[kb], 0, 0, 0);
        }

        // online softmax (rows q = w*16 + (L>>4)*4 + r; cols key = kb*16 + (L&15))
        float al[4];
        float pb[4][4];
        #pragma unroll
        for (int r = 0; r < 4; r++) {
            float m = fmaxf(fmaxf(s[0][r], s[1][r]), fmaxf(s[2][r], s[3][r])) * 0.125f;
            m = fmaxf(m, __shfl_xor(m, 1));
            m = fmaxf(m, __shfl_xor(m, 2));
            m = fmaxf(m, __shfl_xor(m, 4));
            m = fmaxf(m, __shfl_xor(m, 8));
            const float mn = fmaxf(m_run[r], m);
            al[r] = __expf(m_run[r] - mn);
            m_run[r] = mn;
        }
        float ps[4] = {0.f, 0.f, 0.f, 0.f};
        #pragma unroll
        for (int kb = 0; kb < 4; kb++)
            #pragma unroll
            for (int r = 0; r < 4; r++) {
                const float p = __expf(s[kb][r] * 0.125f - m_run[r]);
                pb[kb][r] = p;
                ps[r] += p;
            }
        #pragma unroll
        for (int r = 0; r < 4; r++) {
            ps[r] += __shfl_xor(ps[r], 1);
            ps[r] += __shfl_xor(ps[r], 2);
            ps[r] += __shfl_xor(ps[r], 4);
            ps[r] += __shfl_xor(ps[r], 8);
            l_run[r] = l_run[r] * al[r] + ps[r];
        }
        #pragma unroll
        for (int nb = 0; nb < 4; nb++)
            #pragma unroll
            for (int r = 0; r < 4; r++) acc[nb][r] *= al[r];

        // P -> wave-private LDS ([q][key], stride 72)
        u16* pw = &Ps[w][0];
        #pragma unroll
        for (int kb = 0; kb < 4; kb++)
            #pragma unroll
            for (int r = 0; r < 4; r++)
                pw[((L >> 4) * 4 + r) * 72 + kb * 16 + (L & 15)] = f2bf(pb[kb][r]);

        // PV: A = P [q][key], B = Vt [dim][key]
        const bf16x8 ap0 = *(const bf16x8*)&Ps[w][(L & 15) * 72 +      (L >> 4) * 8];
        const bf16x8 ap1 = *(const bf16x8*)&Ps[w][(L & 15) * 72 + 32 + (L >> 4) * 8];
        #pragma unroll
        for (int nb = 0; nb < 4; nb++) {
            const int drow = nb * 16 + (L & 15);
            const bf16x8 bv0 = *(const bf16x8*)&Vs[drow * 64 + (((L >> 4)     ^ (L & 7)) * 8)];
            const bf16x8 bv1 = *(const bf16x8*)&Vs[drow * 64 + (((4 + (L >> 4)) ^ (L & 7)) * 8)];
            acc[nb] = __builtin_amdgcn_mfma_f32_16x16x32_bf16(ap0, bv0, acc[nb], 0, 0, 0);
            acc[nb] = __builtin_amdgcn_mfma_f32_16x16x32_bf16(ap1, bv1, acc[nb], 0, 0, 0);
        }
    }

    float inv[4];
    #pragma unroll
    for (int r = 0; r < 4; r++) inv[r] = 1.0f / l_run[r];
    #pragma unroll
    for (int nb = 0; nb < 4; nb++)
        #pragma unroll
        for (int r = 0; r < 4; r++) {
            const int q = qt * 64 + w * 16 + (L >> 4) * 4 + r;
            const int d = nb * 16 + (L & 15);
            attno[(size_t)(b * NPd + q) * Cd + hh * 64 + d] = f2bf(acc[nb][r] * inv[r]);
        }
}

// ---------------------------------------------------------------------------
extern "C" void kernel_launch(void* const* d_in, const int* in_sizes, int n_in,
                              void* d_out, int out_size, void* d_ws, size_t ws_size,
                              hipStream_t stream) {
    const float* x       = (const float*)d_in[0];
    const float* cache_k = (const float*)d_in[1];
    const float* cache_v = (const float*)d_in[2];
    const void*  mask    = d_in[3];
    const float* qkv_w   = (const float*)d_in[4];
    const float* qkv_b   = (const float*)d_in[5];
    const float* proj_w  = (const float*)d_in[6];
    const float* proj_b  = (const float*)d_in[7];
    const float* n1_g    = (const float*)d_in[8];
    const float* n1_b    = (const float*)d_in[9];
    const float* n2_g    = (const float*)d_in[10];
    const float* n2_b    = (const float*)d_in[11];
    const float* fc1_w   = (const float*)d_in[12];
    const float* fc1_b   = (const float*)d_in[13];
    const float* fc2_w   = (const float*)d_in[14];
    const float* fc2_b   = (const float*)d_in[15];
    float* out = (float*)d_out;

    const size_t MR = (size_t)Bd * NPd;           // 8192 rows
    char* ws = (char*)d_ws;
    int*   srcArr = (int*)ws;                                     // 64 KB
    float* x2     = (float*)(ws + 65536);                         // 33.55 MB
    u16*   h      = (u16*)(x2 + MR * Cd);                         // 16.78 MB
    u16*   attno  = h + MR * Cd;                                  // 16.78 MB
    u16*   qkv    = attno + MR * Cd;                              // 50.33 MB bf16
    u16*   Kb     = qkv + MR * 3 * Cd;                            // 33.55 MB
    u16*   Vtb    = Kb + (size_t)Bd * Hd * Nd * HDd;              // 33.55 MB
    u16*   m1     = qkv;            // 67.1 MB, reuses dead qkv+Kb region
    u16*   qkv_wt = Vtb + (size_t)Bd * Hd * Nd * HDd;             // 6.29 MB
    u16*   proj_wt= qkv_wt + (size_t)3 * Cd * Cd;                 // 2.10 MB
    u16*   fc1_wt = proj_wt + (size_t)Cd * Cd;                    // 8.39 MB
    u16*   fc2_wt = fc1_wt + (size_t)Cd * HIDd;                   // 8.39 MB

    build_src<<<Bd, 256, 0, stream>>>(mask, srcArr);
    conv_t<<<dim3(3 * Cd / 32, Cd / 32),  256, 0, stream>>>(qkv_w,  qkv_wt,  Cd,   3 * Cd);
    conv_t<<<dim3(Cd / 32, Cd / 32),      256, 0, stream>>>(proj_w, proj_wt, Cd,   Cd);
    conv_t<<<dim3(HIDd / 32, Cd / 32),    256, 0, stream>>>(fc1_w,  fc1_wt,  Cd,   HIDd);
    conv_t<<<dim3(Cd / 32, HIDd / 32),    256, 0, stream>>>(fc2_w,  fc2_wt,  HIDd, Cd);

    ln_kernel<<<MR, 256, 0, stream>>>(x, n1_g, n1_b, h);
    gemm_mfma<0, u16><<<dim3(3 * Cd / 128, MR / 128), 256, 0, stream>>>(h, qkv_wt, qkv_b, nullptr, qkv, Cd, 3 * Cd);
    kv_cast<<<Bd * Hd * (Nd / 64), 256, 0, stream>>>(qkv, cache_k, cache_v, srcArr, Kb, Vtb);
    attn_mfma<<<dim3(Bd * Hd, NPd / 64), 256, 0, stream>>>(qkv, Kb, Vtb, attno);
    gemm_mfma<1, float><<<dim3(Cd / 128, MR / 128), 256, 0, stream>>>(attno, proj_wt, proj_b, x, x2, Cd, Cd);
    ln_kernel<<<MR, 256, 0, stream>>>(x2, n2_g, n2_b, h);
    gemm_mfma<2, u16><<<dim3(HIDd / 128, MR / 128), 256, 0, stream>>>(h, fc1_wt, fc1_b, nullptr, m1, Cd, HIDd);
    gemm_mfma<1, float><<<dim3(Cd / 128, MR / 128), 256, 0, stream>>>(m1, fc2_wt, fc2_b, x2, out, HIDd, Cd);
}